// Round 2
// baseline (263.180 us; speedup 1.0000x reference)
//
#include <hip/hip_runtime.h>
#include <hip/hip_fp16.h>
#include <math.h>

#define BB 128
#define FF 256
#define NN 2000

// -------- K1: convert x -> fp16 AND row max (one wave per row) --------
__global__ __launch_bounds__(256) void k_convmax(const float* __restrict__ x,
                                                 __half* __restrict__ xh,
                                                 float* __restrict__ glb) {
    int row  = (blockIdx.x << 2) | (threadIdx.x >> 6);  // 4 waves/block
    int lane = threadIdx.x & 63;
    const float4* src = (const float4*)(x + (size_t)row * NN);
    float2*       dst = (float2*)(xh + (size_t)row * NN);   // half4 = 8B
    float m = -INFINITY;
    for (int i = lane; i < NN / 4; i += 64) {
        float4 v = src[i];
        m = fmaxf(m, fmaxf(fmaxf(v.x, v.y), fmaxf(v.z, v.w)));
        union { __half2 h; float f; } u0, u1;
        u0.h = __floats2half2_rn(v.x, v.y);
        u1.h = __floats2half2_rn(v.z, v.w);
        dst[i] = make_float2(u0.f, u1.f);
    }
#pragma unroll
    for (int off = 32; off; off >>= 1) m = fmaxf(m, __shfl_xor(m, off));
    if (!lane) glb[row] = m;
}

// -------- K2: per-batch dense prep -> cK[b,f], cK0[b] (fp32 x for gather) --------
__global__ __launch_bounds__(256) void k_prep(
    const float* __restrict__ x, const int* __restrict__ lc,
    const float* __restrict__ glb,
    const float* __restrict__ Wg, const float* __restrict__ bg,
    const float* __restrict__ Wnode, const float* __restrict__ bnode,
    const float* __restrict__ Wlc, const float* __restrict__ blc,
    float* __restrict__ cK, float* __restrict__ cK0)
{
    int b = blockIdx.x;
    int f = threadIdx.x;
    __shared__ float s_glb[FF], s_ctx[2 * FF], s_cQ[FF], s_red[FF];
    const float* xb = x + (size_t)b * FF * NN;
    s_glb[f] = glb[b * FF + f];
    int l0 = lc[2 * b], l1 = lc[2 * b + 1];
    s_ctx[f]      = xb[(size_t)f * NN + l0];
    s_ctx[FF + f] = xb[(size_t)f * NN + l1];
    __syncthreads();
    float q = bg[f];
    const float* wg = Wg + (size_t)f * FF;
    for (int j = 0; j < FF; ++j) q = fmaf(wg[j], s_glb[j], q);
    float cq = blc[f] + q;
    const float* wl = Wlc + (size_t)f * 2 * FF;
    for (int j = 0; j < 2 * FF; ++j) cq = fmaf(wl[j], s_ctx[j], cq);
    s_cQ[f]  = cq;
    s_red[f] = cq * bnode[f];
    __syncthreads();
    float ck = 0.f;
    for (int g = 0; g < FF; ++g) ck = fmaf(s_cQ[g], Wnode[(size_t)g * FF + f], ck);
    cK[b * FF + f] = ck;
    for (int s = 128; s > 0; s >>= 1) {
        if (f < s) s_red[f] += s_red[f + s];
        __syncthreads();
    }
    if (f == 0) cK0[b] = s_red[0];
}

// -------- K3: ucj + softmax per batch -> normalized p[b,n] --------
__global__ __launch_bounds__(1024) void k_ucj(
    const __half* __restrict__ xh,
    const float* __restrict__ cK, const float* __restrict__ cK0,
    float* __restrict__ p)
{
    int b    = blockIdx.x;
    int tid  = threadIdx.x;
    int wid  = tid >> 6;
    int lane = tid & 63;
    const __half* xb = xh + (size_t)b * FF * NN;
    __shared__ float s_cK[FF];
    __shared__ float s_red[40];
    const float scale = 0.0625f;

    if (tid < FF) s_cK[tid] = cK[b * FF + tid];
    __syncthreads();

    float u0 = -INFINITY, u1 = -INFINITY;
    if (tid < NN / 2) {
        float a0 = 0.f, a1 = 0.f;
        const __half* xp = xb + 2 * tid;
#pragma unroll 4
        for (int f = 0; f < FF; ++f) {
            float2 v = __half22float2(*(const __half2*)(xp + (size_t)f * NN));
            float  c = s_cK[f];
            a0 = fmaf(c, v.x, a0);
            a1 = fmaf(c, v.y, a1);
        }
        float k0 = cK0[b];
        u0 = (a0 + k0) * scale;
        u1 = (a1 + k0) * scale;
    }
    float m = fmaxf(u0, u1);
#pragma unroll
    for (int off = 32; off; off >>= 1) m = fmaxf(m, __shfl_xor(m, off));
    if (!lane) s_red[wid] = m;
    __syncthreads();
    if (!tid) {
        float mm = s_red[0];
        for (int w = 1; w < 16; ++w) mm = fmaxf(mm, s_red[w]);
        s_red[32] = mm;
    }
    __syncthreads();
    float bm = s_red[32];
    float p0 = 0.f, p1 = 0.f;
    if (tid < NN / 2) {
        p0 = __expf(u0 - bm);
        p1 = __expf(u1 - bm);
    }
    float ps = p0 + p1;
#pragma unroll
    for (int off = 32; off; off >>= 1) ps += __shfl_xor(ps, off);
    __syncthreads();
    if (!lane) s_red[wid] = ps;
    __syncthreads();
    if (!tid) {
        float ss = 0.f;
        for (int w = 0; w < 16; ++w) ss += s_red[w];
        s_red[33] = ss;
    }
    __syncthreads();
    float inv_sum = 1.0f / s_red[33];
    if (tid < NN / 2) {
        p[(size_t)b * NN + 2 * tid]     = p0 * inv_sum;
        p[(size_t)b * NN + 2 * tid + 1] = p1 * inv_sum;
    }
}

// -------- K4: y[b,f] = sum_n p[b,n]*xh[b,f,n]  (full-chip: 16 rows/block) --------
__global__ __launch_bounds__(256) void k_ypool(
    const __half* __restrict__ xh, const float* __restrict__ p,
    float* __restrict__ y)
{
    int b    = blockIdx.x >> 4;
    int fblk = (blockIdx.x & 15) << 4;
    int tid  = threadIdx.x;
    int wid  = tid >> 6;
    int lane = tid & 63;
    __shared__ float s_p[NN];
    const float4* p4 = (const float4*)(p + (size_t)b * NN);
    for (int i = tid; i < NN / 4; i += 256) ((float4*)s_p)[i] = p4[i];
    __syncthreads();
    for (int r = 0; r < 4; ++r) {
        int f = fblk + (wid << 2) + r;
        const float2* row = (const float2*)(xh + ((size_t)b * FF + f) * NN);
        float acc = 0.f;
        for (int i = lane; i < NN / 4; i += 64) {
            float2 hv = row[i];
            union { float f; __half2 h; } a, c;
            a.f = hv.x; c.f = hv.y;
            float2 x0 = __half22float2(a.h);
            float2 x1 = __half22float2(c.h);
            float4 pv = ((const float4*)s_p)[i];
            acc = fmaf(x0.x, pv.x, acc);
            acc = fmaf(x0.y, pv.y, acc);
            acc = fmaf(x1.x, pv.z, acc);
            acc = fmaf(x1.y, pv.w, acc);
        }
#pragma unroll
        for (int off = 32; off; off >>= 1) acc += __shfl_xor(acc, off);
        if (!lane) y[b * FF + f] = acc;
    }
}

// -------- K5: dense chain per batch -> cL[b,f], cL0[b] --------
__global__ __launch_bounds__(256) void k_dense(
    const float* __restrict__ y,
    const float* __restrict__ Wnode, const float* __restrict__ bnode,
    const float* __restrict__ Wproj, const float* __restrict__ bproj,
    float* __restrict__ cL, float* __restrict__ cL0)
{
    int b = blockIdx.x;
    int f = threadIdx.x;
    int wid = f >> 6, lane = f & 63;
    __shared__ float s_y[FF], s_v[FF], s_red[4];
    s_y[f] = y[b * FF + f];
    __syncthreads();
    float a = bnode[FF + f];
    const float* w = Wnode + (size_t)(FF + f) * FF;
    for (int j = 0; j < FF; ++j) a = fmaf(w[j], s_y[j], a);
    s_v[f] = a;
    __syncthreads();
    float nc2 = bproj[f];
    const float* wp = Wproj + (size_t)f * FF;
    for (int j = 0; j < FF; ++j) nc2 = fmaf(wp[j], s_v[j], nc2);
    __syncthreads();
    s_v[f] = nc2;
    __syncthreads();
    float cl = 0.f;
    for (int g = 0; g < FF; ++g) cl = fmaf(s_v[g], Wnode[(size_t)(2 * FF + g) * FF + f], cl);
    cL[b * FF + f] = cl;
    float t = nc2 * bnode[2 * FF + f];
#pragma unroll
    for (int off = 32; off; off >>= 1) t += __shfl_xor(t, off);
    if (!lane) s_red[wid] = t;
    __syncthreads();
    if (!f) cL0[b] = s_red[0] + s_red[1] + s_red[2] + s_red[3];
}

// -------- K6: logits + tanh (full-chip: 512-col tiles) --------
__global__ __launch_bounds__(256) void k_logits(
    const __half* __restrict__ xh,
    const float* __restrict__ cL, const float* __restrict__ cL0,
    float* __restrict__ out)
{
    int b = blockIdx.x >> 2;
    int q = blockIdx.x & 3;
    int tid = threadIdx.x;
    __shared__ float s_cL[FF];
    s_cL[tid] = cL[b * FF + tid];
    __syncthreads();
    int n = (q << 9) + 2 * tid;
    if (n < NN) {
        const __half* xp = xh + (size_t)b * FF * NN + n;
        float a0 = 0.f, a1 = 0.f;
#pragma unroll 4
        for (int f = 0; f < FF; ++f) {
            float2 v = __half22float2(*(const __half2*)(xp + (size_t)f * NN));
            float  c = s_cL[f];
            a0 = fmaf(c, v.x, a0);
            a1 = fmaf(c, v.y, a1);
        }
        float c0 = cL0[b];
        float l0 = (a0 + c0) * 0.0625f;
        float l1 = (a1 + c0) * 0.0625f;
        out[(size_t)b * NN + n]     = tanhf(l0) * 10.f;
        out[(size_t)b * NN + n + 1] = tanhf(l1) * 10.f;
    }
}

extern "C" void kernel_launch(void* const* d_in, const int* in_sizes, int n_in,
                              void* d_out, int out_size, void* d_ws, size_t ws_size,
                              hipStream_t stream) {
    const float* x     = (const float*)d_in[0];
    const int*   lc    = (const int*)d_in[1];
    const float* Wg    = (const float*)d_in[2];
    const float* bg    = (const float*)d_in[3];
    const float* Wnode = (const float*)d_in[4];
    const float* bnode = (const float*)d_in[5];
    const float* Wlc   = (const float*)d_in[6];
    const float* blc   = (const float*)d_in[7];
    const float* Wproj = (const float*)d_in[8];
    const float* bproj = (const float*)d_in[9];
    float* out = (float*)d_out;

    float* ws   = (float*)d_ws;
    float* glb  = ws + 0;          // B*F = 32768
    float* cK   = ws + 40960;      // B*F
    float* cK0  = ws + 81920;      // B
    float* p    = ws + 90112;      // B*N = 256000
    float* y    = ws + 360448;     // B*F
    float* cL   = ws + 393216;     // B*F
    float* cL0  = ws + 425984;     // B
    __half* xh  = (__half*)(ws + (1 << 20));  // byte offset 4 MB, 131 MB

    k_convmax<<<BB * FF / 4, 256, 0, stream>>>(x, xh, glb);
    k_prep   <<<BB, 256, 0, stream>>>(x, lc, glb, Wg, bg, Wnode, bnode, Wlc, blc, cK, cK0);
    k_ucj    <<<BB, 1024, 0, stream>>>(xh, cK, cK0, p);
    k_ypool  <<<BB * 16, 256, 0, stream>>>(xh, p, y);
    k_dense  <<<BB, 256, 0, stream>>>(y, Wnode, bnode, Wproj, bproj, cL, cL0);
    k_logits <<<BB * 4, 256, 0, stream>>>(xh, cL, cL0, out);
}

// Round 3
// 202.365 us; speedup vs baseline: 1.3005x; 1.3005x over previous
//
#include <hip/hip_runtime.h>
#include <hip/hip_fp16.h>
#include <math.h>

#define BB 128
#define FF 256
#define NN 2000

typedef float f32x4 __attribute__((ext_vector_type(4)));
union H8 { f32x4 v; __half2 h[4]; };

// -------- K1: convert x -> fp16 AND row max (one wave per row, 16B lds/sts) --------
__global__ __launch_bounds__(256) void k_convmax(const float* __restrict__ x,
                                                 __half* __restrict__ xh,
                                                 float* __restrict__ glb) {
    int row  = (blockIdx.x << 2) | (threadIdx.x >> 6);
    int lane = threadIdx.x & 63;
    const f32x4* src = (const f32x4*)(x + (size_t)row * NN);
    f32x4*       dst = (f32x4*)(xh + (size_t)row * NN);
    float m = -INFINITY;
    for (int i = lane; i < 250; i += 64) {
        f32x4 a = __builtin_nontemporal_load(src + 2 * i);
        f32x4 b = __builtin_nontemporal_load(src + 2 * i + 1);
        m = fmaxf(m, fmaxf(fmaxf(a.x, a.y), fmaxf(a.z, a.w)));
        m = fmaxf(m, fmaxf(fmaxf(b.x, b.y), fmaxf(b.z, b.w)));
        H8 o;
        o.h[0] = __floats2half2_rn(a.x, a.y);
        o.h[1] = __floats2half2_rn(a.z, a.w);
        o.h[2] = __floats2half2_rn(b.x, b.y);
        o.h[3] = __floats2half2_rn(b.z, b.w);
        dst[i] = o.v;
    }
#pragma unroll
    for (int off = 32; off; off >>= 1) m = fmaxf(m, __shfl_xor(m, off));
    if (!lane) glb[row] = m;
}

// -------- K2: per-batch dense prep -> cK[b,f], cK0[b] (fp32 x for gather) --------
__global__ __launch_bounds__(256) void k_prep(
    const float* __restrict__ x, const int* __restrict__ lc,
    const float* __restrict__ glb,
    const float* __restrict__ Wg, const float* __restrict__ bg,
    const float* __restrict__ Wnode, const float* __restrict__ bnode,
    const float* __restrict__ Wlc, const float* __restrict__ blc,
    float* __restrict__ cK, float* __restrict__ cK0)
{
    int b = blockIdx.x;
    int f = threadIdx.x;
    __shared__ float s_glb[FF], s_ctx[2 * FF], s_cQ[FF], s_red[FF];
    const float* xb = x + (size_t)b * FF * NN;
    s_glb[f] = glb[b * FF + f];
    int l0 = lc[2 * b], l1 = lc[2 * b + 1];
    s_ctx[f]      = xb[(size_t)f * NN + l0];
    s_ctx[FF + f] = xb[(size_t)f * NN + l1];
    __syncthreads();
    float q = bg[f];
    const float* wg = Wg + (size_t)f * FF;
    for (int j = 0; j < FF; ++j) q = fmaf(wg[j], s_glb[j], q);
    float cq = blc[f] + q;
    const float* wl = Wlc + (size_t)f * 2 * FF;
    for (int j = 0; j < 2 * FF; ++j) cq = fmaf(wl[j], s_ctx[j], cq);
    s_cQ[f]  = cq;
    s_red[f] = cq * bnode[f];
    __syncthreads();
    float ck = 0.f;
    for (int g = 0; g < FF; ++g) ck = fmaf(s_cQ[g], Wnode[(size_t)g * FF + f], ck);
    cK[b * FF + f] = ck;
    for (int s = 128; s > 0; s >>= 1) {
        if (f < s) s_red[f] += s_red[f + s];
        __syncthreads();
    }
    if (f == 0) cK0[b] = s_red[0];
}

// -------- K3: u[b,n] = cK[b]·xh[b,:,n]  (4 blocks/batch, 512-col stripes) --------
__global__ __launch_bounds__(256) void k_ucj(const __half* __restrict__ xh,
                                             const float* __restrict__ cK,
                                             float* __restrict__ u)
{
    int b = blockIdx.x >> 2, s = blockIdx.x & 3;
    int tid = threadIdx.x, w = tid >> 6, lane = tid & 63;
    __shared__ float s_cK[FF];
    __shared__ float s_part[4][512];
    s_cK[tid] = cK[b * FF + tid];
    __syncthreads();
    int n0 = s << 9;
    int nbase = n0 + (lane << 3);
    float a0 = 0, a1 = 0, a2 = 0, a3 = 0, a4 = 0, a5 = 0, a6 = 0, a7 = 0;
    if (nbase < NN) {
        const __half* rp = xh + (size_t)(b * FF + (w << 6)) * NN + nbase;
#pragma unroll 4
        for (int fi = 0; fi < 64; ++fi) {
            H8 hv; hv.v = *(const f32x4*)rp;
            rp += NN;
            float c = s_cK[(w << 6) + fi];
            float2 q0 = __half22float2(hv.h[0]);
            float2 q1 = __half22float2(hv.h[1]);
            float2 q2 = __half22float2(hv.h[2]);
            float2 q3 = __half22float2(hv.h[3]);
            a0 = fmaf(c, q0.x, a0); a1 = fmaf(c, q0.y, a1);
            a2 = fmaf(c, q1.x, a2); a3 = fmaf(c, q1.y, a3);
            a4 = fmaf(c, q2.x, a4); a5 = fmaf(c, q2.y, a5);
            a6 = fmaf(c, q3.x, a6); a7 = fmaf(c, q3.y, a7);
        }
    }
    int cb = lane << 3;
    s_part[w][cb + 0] = a0; s_part[w][cb + 1] = a1;
    s_part[w][cb + 2] = a2; s_part[w][cb + 3] = a3;
    s_part[w][cb + 4] = a4; s_part[w][cb + 5] = a5;
    s_part[w][cb + 6] = a6; s_part[w][cb + 7] = a7;
    __syncthreads();
    for (int c = tid; c < 512; c += 256) {
        int n = n0 + c;
        if (n < NN)
            u[(size_t)b * NN + n] =
                s_part[0][c] + s_part[1][c] + s_part[2][c] + s_part[3][c];
    }
}

// -------- K4: softmax over u -> normalized p --------
__global__ __launch_bounds__(256) void k_softmax(const float* __restrict__ u,
                                                 const float* __restrict__ cK0,
                                                 float* __restrict__ p)
{
    int b = blockIdx.x, tid = threadIdx.x, w = tid >> 6, lane = tid & 63;
    __shared__ float s_red[8];
    float k0 = cK0[b];
    const float scale = 0.0625f;
    float v[8];
    float m = -INFINITY;
#pragma unroll
    for (int j = 0; j < 8; ++j) {
        int n = (j << 8) + tid;
        float t = -INFINITY;
        if (n < NN) t = (u[(size_t)b * NN + n] + k0) * scale;
        v[j] = t;
        m = fmaxf(m, t);
    }
#pragma unroll
    for (int off = 32; off; off >>= 1) m = fmaxf(m, __shfl_xor(m, off));
    if (!lane) s_red[w] = m;
    __syncthreads();
    m = fmaxf(fmaxf(s_red[0], s_red[1]), fmaxf(s_red[2], s_red[3]));
    float sum = 0.f;
#pragma unroll
    for (int j = 0; j < 8; ++j) {
        float e = (v[j] > -INFINITY) ? __expf(v[j] - m) : 0.f;
        v[j] = e;
        sum += e;
    }
#pragma unroll
    for (int off = 32; off; off >>= 1) sum += __shfl_xor(sum, off);
    __syncthreads();
    if (!lane) s_red[w] = sum;
    __syncthreads();
    float inv = 1.0f / (s_red[0] + s_red[1] + s_red[2] + s_red[3]);
#pragma unroll
    for (int j = 0; j < 8; ++j) {
        int n = (j << 8) + tid;
        if (n < NN) p[(size_t)b * NN + n] = v[j] * inv;
    }
}

// -------- K5: y[b,f] = sum_n p[b,n]*xh[b,f,n]  (16 rows/block, 16B loads) --------
__global__ __launch_bounds__(256) void k_ypool(const __half* __restrict__ xh,
                                               const float* __restrict__ p,
                                               float* __restrict__ y)
{
    int b = blockIdx.x >> 4, fblk = (blockIdx.x & 15) << 4;
    int tid = threadIdx.x, w = tid >> 6, lane = tid & 63;
    const float4* pb = (const float4*)(p + (size_t)b * NN);
#pragma unroll
    for (int r = 0; r < 4; ++r) {
        int f = fblk + (w << 2) + r;
        const f32x4* row = (const f32x4*)(xh + ((size_t)b * FF + f) * NN);
        float acc = 0.f;
        for (int i = lane; i < 250; i += 64) {
            H8 hv; hv.v = row[i];
            float4 pa = pb[2 * i];
            float4 pc = pb[2 * i + 1];
            float2 q0 = __half22float2(hv.h[0]);
            float2 q1 = __half22float2(hv.h[1]);
            float2 q2 = __half22float2(hv.h[2]);
            float2 q3 = __half22float2(hv.h[3]);
            acc = fmaf(q0.x, pa.x, acc); acc = fmaf(q0.y, pa.y, acc);
            acc = fmaf(q1.x, pa.z, acc); acc = fmaf(q1.y, pa.w, acc);
            acc = fmaf(q2.x, pc.x, acc); acc = fmaf(q2.y, pc.y, acc);
            acc = fmaf(q3.x, pc.z, acc); acc = fmaf(q3.y, pc.w, acc);
        }
#pragma unroll
        for (int off = 32; off; off >>= 1) acc += __shfl_xor(acc, off);
        if (!lane) y[b * FF + f] = acc;
    }
}

// -------- K6: dense chain per batch -> cL[b,f], cL0[b] --------
__global__ __launch_bounds__(256) void k_dense(
    const float* __restrict__ y,
    const float* __restrict__ Wnode, const float* __restrict__ bnode,
    const float* __restrict__ Wproj, const float* __restrict__ bproj,
    float* __restrict__ cL, float* __restrict__ cL0)
{
    int b = blockIdx.x;
    int f = threadIdx.x;
    int wid = f >> 6, lane = f & 63;
    __shared__ float s_y[FF], s_v[FF], s_red[4];
    s_y[f] = y[b * FF + f];
    __syncthreads();
    float a = bnode[FF + f];
    const float* w = Wnode + (size_t)(FF + f) * FF;
    for (int j = 0; j < FF; ++j) a = fmaf(w[j], s_y[j], a);
    s_v[f] = a;
    __syncthreads();
    float nc2 = bproj[f];
    const float* wp = Wproj + (size_t)f * FF;
    for (int j = 0; j < FF; ++j) nc2 = fmaf(wp[j], s_v[j], nc2);
    __syncthreads();
    s_v[f] = nc2;
    __syncthreads();
    float cl = 0.f;
    for (int g = 0; g < FF; ++g) cl = fmaf(s_v[g], Wnode[(size_t)(2 * FF + g) * FF + f], cl);
    cL[b * FF + f] = cl;
    float t = nc2 * bnode[2 * FF + f];
#pragma unroll
    for (int off = 32; off; off >>= 1) t += __shfl_xor(t, off);
    if (!lane) s_red[wid] = t;
    __syncthreads();
    if (!f) cL0[b] = s_red[0] + s_red[1] + s_red[2] + s_red[3];
}

// -------- K7: logits + tanh (4 blocks/batch, same structure as K3) --------
__global__ __launch_bounds__(256) void k_logits(const __half* __restrict__ xh,
                                                const float* __restrict__ cL,
                                                const float* __restrict__ cL0,
                                                float* __restrict__ out)
{
    int b = blockIdx.x >> 2, s = blockIdx.x & 3;
    int tid = threadIdx.x, w = tid >> 6, lane = tid & 63;
    __shared__ float s_cL[FF];
    __shared__ float s_part[4][512];
    s_cL[tid] = cL[b * FF + tid];
    __syncthreads();
    int n0 = s << 9;
    int nbase = n0 + (lane << 3);
    float a0 = 0, a1 = 0, a2 = 0, a3 = 0, a4 = 0, a5 = 0, a6 = 0, a7 = 0;
    if (nbase < NN) {
        const __half* rp = xh + (size_t)(b * FF + (w << 6)) * NN + nbase;
#pragma unroll 4
        for (int fi = 0; fi < 64; ++fi) {
            H8 hv; hv.v = *(const f32x4*)rp;
            rp += NN;
            float c = s_cL[(w << 6) + fi];
            float2 q0 = __half22float2(hv.h[0]);
            float2 q1 = __half22float2(hv.h[1]);
            float2 q2 = __half22float2(hv.h[2]);
            float2 q3 = __half22float2(hv.h[3]);
            a0 = fmaf(c, q0.x, a0); a1 = fmaf(c, q0.y, a1);
            a2 = fmaf(c, q1.x, a2); a3 = fmaf(c, q1.y, a3);
            a4 = fmaf(c, q2.x, a4); a5 = fmaf(c, q2.y, a5);
            a6 = fmaf(c, q3.x, a6); a7 = fmaf(c, q3.y, a7);
        }
    }
    int cb = lane << 3;
    s_part[w][cb + 0] = a0; s_part[w][cb + 1] = a1;
    s_part[w][cb + 2] = a2; s_part[w][cb + 3] = a3;
    s_part[w][cb + 4] = a4; s_part[w][cb + 5] = a5;
    s_part[w][cb + 6] = a6; s_part[w][cb + 7] = a7;
    __syncthreads();
    float cl0 = cL0[b];
    const float scale = 0.0625f;
    for (int c = tid; c < 512; c += 256) {
        int n = n0 + c;
        if (n < NN) {
            float l = (s_part[0][c] + s_part[1][c] + s_part[2][c] + s_part[3][c] + cl0) * scale;
            out[(size_t)b * NN + n] = tanhf(l) * 10.f;
        }
    }
}

extern "C" void kernel_launch(void* const* d_in, const int* in_sizes, int n_in,
                              void* d_out, int out_size, void* d_ws, size_t ws_size,
                              hipStream_t stream) {
    const float* x     = (const float*)d_in[0];
    const int*   lc    = (const int*)d_in[1];
    const float* Wg    = (const float*)d_in[2];
    const float* bg    = (const float*)d_in[3];
    const float* Wnode = (const float*)d_in[4];
    const float* bnode = (const float*)d_in[5];
    const float* Wlc   = (const float*)d_in[6];
    const float* blc   = (const float*)d_in[7];
    const float* Wproj = (const float*)d_in[8];
    const float* bproj = (const float*)d_in[9];
    float* out = (float*)d_out;

    float* ws   = (float*)d_ws;
    float* glb  = ws + 0;          // B*F
    float* cK   = ws + 40960;      // B*F
    float* cK0  = ws + 81920;      // B
    float* u    = ws + 90112;      // B*N
    float* p    = ws + 360448;     // B*N
    float* y    = ws + 630784;     // B*F
    float* cL   = ws + 663552;     // B*F
    float* cL0  = ws + 696320;     // B
    __half* xh  = (__half*)(ws + (1 << 20));  // 131 MB at 4 MB offset

    k_convmax<<<BB * FF / 4, 256, 0, stream>>>(x, xh, glb);
    k_prep   <<<BB, 256, 0, stream>>>(x, lc, glb, Wg, bg, Wnode, bnode, Wlc, blc, cK, cK0);
    k_ucj    <<<BB * 4, 256, 0, stream>>>(xh, cK, u);
    k_softmax<<<BB, 256, 0, stream>>>(u, cK0, p);
    k_ypool  <<<BB * 16, 256, 0, stream>>>(xh, p, y);
    k_dense  <<<BB, 256, 0, stream>>>(y, Wnode, bnode, Wproj, bproj, cL, cL0);
    k_logits <<<BB * 4, 256, 0, stream>>>(xh, cL, cL0, out);
}